// Round 2
// baseline (3294.486 us; speedup 1.0000x reference)
//
#include <hip/hip_runtime.h>
#include <stdint.h>

// NAS LSTM controller on MI355X. H=2048, 8 categories, 2 cells x (2 warmup + 6 nodes).
// Sequential chain of 64 LSTM steps; exact JAX threefry RNG replication for sampling.
// Round 2: gie precompute (w_ih @ emb[j] for all 9 j) skips w_ih reads on embedding-x
// steps; one-wave-per-row LSTM (8192 waves); last-block fused samplers.

#define HDIM 2048
#define NCAT 8
#define NROWS 8192
#define PARTITIONABLE 1   // modern JAX (>=0.4.30) default threefry mode

// ---------------- workspace float offsets ----------------
#define WS_H0    0
#define WS_H1    2048
#define WS_C     4096
#define WS_X     6144
#define WS_T2    8192
#define WS_ANCH  10240     // 8 x 2048
#define WS_AW1   26624     // 8 x 2048
#define WS_SCAL  43008     // [ent, lp]
#define WS_XCTL  43010     // int xmode, int xidx
#define WS_NK    43012     // 24 u32 node keys
#define WS_CTR   43072     // 64 int counters
#define WS_BIAS  43264     // 8192 (b_ih + b_hh)
#define WS_GIE   51456     // 9 x 8192 (w_ih@emb[j] + bias)

// ---------------- threefry2x32 (20 rounds) ----------------
__device__ __forceinline__ unsigned rotl32(unsigned v, int r){ return (v<<r)|(v>>(32-r)); }

__device__ inline void tf_block(unsigned k0, unsigned k1, unsigned x0, unsigned x1,
                                unsigned& o0, unsigned& o1){
  unsigned ks0=k0, ks1=k1, ks2=0x1BD11BDAu ^ k0 ^ k1;
  const int ra[4]={13,15,26,6};
  const int rb[4]={17,29,16,24};
  x0 += ks0; x1 += ks1;
  #pragma unroll
  for (int i=0;i<4;++i){ x0+=x1; x1=rotl32(x1,ra[i]); x1^=x0; }
  x0+=ks1; x1+=ks2+1u;
  #pragma unroll
  for (int i=0;i<4;++i){ x0+=x1; x1=rotl32(x1,rb[i]); x1^=x0; }
  x0+=ks2; x1+=ks0+2u;
  #pragma unroll
  for (int i=0;i<4;++i){ x0+=x1; x1=rotl32(x1,ra[i]); x1^=x0; }
  x0+=ks0; x1+=ks1+3u;
  #pragma unroll
  for (int i=0;i<4;++i){ x0+=x1; x1=rotl32(x1,rb[i]); x1^=x0; }
  x0+=ks1; x1+=ks2+4u;
  #pragma unroll
  for (int i=0;i<4;++i){ x0+=x1; x1=rotl32(x1,ra[i]); x1^=x0; }
  x0+=ks2; x1+=ks0+5u;
  o0=x0; o1=x1;
}

__device__ __forceinline__ float sigm(float z){ return 1.0f/(1.0f+expf(-z)); }

__device__ inline int sample_and_stats(const float* logits, unsigned k0, unsigned k1,
                                       float* scal /* [ent, lp] */){
  unsigned bits[NCAT];
#if PARTITIONABLE
  #pragma unroll
  for (int i=0;i<NCAT;++i){ unsigned a,b; tf_block(k0,k1,0u,(unsigned)i,a,b); bits[i]=a^b; }
#else
  #pragma unroll
  for (int i=0;i<4;++i){ unsigned a,b; tf_block(k0,k1,(unsigned)i,(unsigned)(i+4),a,b); bits[i]=a; bits[i+4]=b; }
#endif
  const float tiny = 1.1754943508222875e-38f;
  int best=0; float bv=-3.4e38f;
  #pragma unroll
  for (int j=0;j<NCAT;++j){
    float f = __uint_as_float((bits[j]>>9)|0x3f800000u) - 1.0f;
    float u = fmaxf(tiny, f*(1.0f-tiny)+tiny);
    float g = -logf(-logf(u));
    float vv = g + logits[j];
    if (vv > bv){ bv=vv; best=j; }     // first-max wins, like jnp.argmax
  }
  float m=-3.4e38f;
  #pragma unroll
  for (int j=0;j<NCAT;++j) m = fmaxf(m, logits[j]);
  float se=0.f;
  #pragma unroll
  for (int j=0;j<NCAT;++j) se += expf(logits[j]-m);
  float lse = logf(se);
  scal[1] += (m + lse - logits[best]);            // lp += -logp[idx]
  float ent = 0.f;
  #pragma unroll
  for (int j=0;j<NCAT;++j){
    float lpj = logits[j]-m-lse;
    float p = expf(lpj);
    if (p > 0.f) ent -= p*lpj;                    // where(p>0, p*logp, 0)
  }
  scal[0] += ent;
  return best;
}

// ---------------- precompute: gie[j][r] = w_ih[r]·emb[j] + b_ih[r] + b_hh[r] ----------------
__global__ __launch_bounds__(256) void k_pre(const float* __restrict__ w_ih,
    const float* __restrict__ b_ih, const float* __restrict__ b_hh,
    const float* __restrict__ emb, float* __restrict__ gie, float* __restrict__ bias)
{
  int wv = threadIdx.x>>6, ln = threadIdx.x&63;
  int r = blockIdx.x*4 + wv;                   // 2048 blocks -> 8192 rows
  const float4* wr = (const float4*)(w_ih + (size_t)r*HDIM);
  const float4* e4 = (const float4*)emb;
  float acc[9];
  #pragma unroll
  for (int j=0;j<9;++j) acc[j]=0.f;
  for (int it=0; it<8; ++it){
    float4 a = wr[ln+it*64];
    #pragma unroll
    for (int j=0;j<9;++j){
      float4 e = e4[j*512 + ln + it*64];
      acc[j] += a.x*e.x + a.y*e.y + a.z*e.z + a.w*e.w;
    }
  }
  #pragma unroll
  for (int j=0;j<9;++j){
    float s = acc[j];
    #pragma unroll
    for (int m=32;m;m>>=1) s += __shfl_xor(s,m,64);
    acc[j]=s;
  }
  if (ln==0){
    float b = b_ih[r] + b_hh[r];
    bias[r] = b;
    #pragma unroll
    for (int j=0;j<9;++j) gie[(size_t)j*NROWS + r] = acc[j] + b;
  }
}

// ---------------- per-cell init ----------------
__global__ __launch_bounds__(256) void k_init(float* ws, const int* __restrict__ seedp, int cell){
  int t = threadIdx.x;
  float* anch = ws + WS_ANCH;
  float* aw1  = ws + WS_AW1;
  for (int i=t;i<NCAT*HDIM;i+=256){ anch[i]=0.f; aw1[i]=0.f; }
  if (cell==0){
    for (int i=t;i<HDIM;i+=256){ ws[WS_H0+i]=0.f; ws[WS_C+i]=0.f; }
    for (int i=t;i<64;i+=256) ((int*)(ws+WS_CTR))[i]=0;
  }
  if (t<2) ((int*)(ws+WS_XCTL))[t] = 0;       // xmode=0, xidx=0 (x = emb[0])
  if (t==0 && cell==0){
    ws[WS_SCAL]=0.f; ws[WS_SCAL+1]=0.f;
    unsigned* nk = (unsigned*)(ws + WS_NK);
    unsigned seed = (unsigned)seedp[0];
    unsigned K0=0u, K1=seed;
    unsigned ck[2][2];
#if PARTITIONABLE
    tf_block(K0,K1,0u,0u,ck[0][0],ck[0][1]);   // k1
    tf_block(K0,K1,0u,1u,ck[1][0],ck[1][1]);   // k2
    for (int cc=0;cc<2;++cc)
      for (int i=0;i<6;++i)
        tf_block(ck[cc][0],ck[cc][1],0u,(unsigned)i, nk[(cc*6+i)*2], nk[(cc*6+i)*2+1]);
#else
    unsigned a0,a1,b0,b1;
    tf_block(K0,K1,0u,2u,a0,a1);
    tf_block(K0,K1,1u,3u,b0,b1);
    ck[0][0]=a0; ck[0][1]=b0; ck[1][0]=a1; ck[1][1]=b1;
    for (int cc=0;cc<2;++cc){
      unsigned y0[6], y1[6];
      for (int i=0;i<6;++i) tf_block(ck[cc][0],ck[cc][1],(unsigned)i,(unsigned)(i+6),y0[i],y1[i]);
      unsigned flat[12];
      for (int i=0;i<6;++i){ flat[i]=y0[i]; flat[6+i]=y1[i]; }
      for (int i=0;i<6;++i){ nk[(cc*6+i)*2]=flat[2*i]; nk[(cc*6+i)*2+1]=flat[2*i+1]; }
    }
#endif
  }
}

// ---------------- LSTM step: one wave per gate-row; optional fused op-sample ----------------
// xmode (ws): 0 -> x = emb[xidx], w_ih part precomputed in gie
//             1 -> x = ws.x (real anchor), compute w_ih row dot
//             2 -> x = 0 (zero anchor), w_ih part = 0
__global__ __launch_bounds__(256) void k_lstm(
    const float* __restrict__ w_ih, const float* __restrict__ w_hh,
    const float* __restrict__ bias, const float* __restrict__ gie,
    const int* __restrict__ xctl, const float* __restrict__ x,
    const float* __restrict__ h_in, float* __restrict__ h_out, float* __restrict__ c,
    int post, int* __restrict__ ctr,
    const float* __restrict__ wopt, const float* __restrict__ bopt,
    float* __restrict__ scal, const unsigned* __restrict__ nk,
    int key_ofs, int isub, float* __restrict__ outslot, int* __restrict__ xctl_w)
{
  int u  = blockIdx.x;              // hidden unit 0..2047
  int wv = threadIdx.x >> 6;        // gate 0..3 (i,f,g,o)
  int ln = threadIdx.x & 63;
  int xmode = xctl[0], xidx = xctl[1];
  size_t r = (size_t)wv*HDIM + u;

  const float4* whr = (const float4*)(w_hh + r*HDIM);
  const float4* h4  = (const float4*)h_in;
  float s = 0.f;
  #pragma unroll
  for (int it=0; it<8; ++it){
    float4 a = whr[ln+it*64]; float4 b = h4[ln+it*64];
    s += a.x*b.x + a.y*b.y + a.z*b.z + a.w*b.w;
  }
  if (xmode==1){
    const float4* wir = (const float4*)(w_ih + r*HDIM);
    const float4* x4  = (const float4*)x;
    #pragma unroll
    for (int it=0; it<8; ++it){
      float4 a = wir[ln+it*64]; float4 b = x4[ln+it*64];
      s += a.x*b.x + a.y*b.y + a.z*b.z + a.w*b.w;
    }
  }
  #pragma unroll
  for (int m=32; m; m>>=1) s += __shfl_xor(s, m, 64);

  __shared__ float gl[4];
  __shared__ int slast;
  __shared__ float sc[NCAT];
  if (ln==0) gl[wv] = s;
  __syncthreads();
  if (threadIdx.x==0){
    float a0,a1,a2,a3;
    if (xmode==0){
      const float* gc = gie + (size_t)xidx*NROWS;
      a0=gc[u]; a1=gc[HDIM+u]; a2=gc[2*HDIM+u]; a3=gc[3*HDIM+u];
    } else {
      a0=bias[u]; a1=bias[HDIM+u]; a2=bias[2*HDIM+u]; a3=bias[3*HDIM+u];
    }
    float gi=gl[0]+a0, gf=gl[1]+a1, gg=gl[2]+a2, go=gl[3]+a3;
    float cn = sigm(gf)*c[u] + sigm(gi)*tanhf(gg);
    c[u] = cn;
    h_out[u] = sigm(go)*tanhf(cn);
    if (post){
      __threadfence();
      int old = atomicAdd(ctr, 1);
      slast = (old == (int)gridDim.x - 1);
    }
  }
  if (!post) return;
  __syncthreads();
  if (!slast) return;
  __threadfence();
  // last block: op logits = w_opt @ h + b_opt, sample, set x = emb[op+1]
  const float4* ho4 = (const float4*)h_out;
  for (int j=wv; j<NCAT; j+=4){
    const float4* wo = (const float4*)(wopt + (size_t)j*HDIM);
    float t = 0.f;
    #pragma unroll
    for (int it=0; it<8; ++it){
      float4 a = wo[ln+it*64]; float4 b = ho4[ln+it*64];
      t += a.x*b.x + a.y*b.y + a.z*b.z + a.w*b.w;
    }
    #pragma unroll
    for (int m=32; m; m>>=1) t += __shfl_xor(t, m, 64);
    if (ln==0) sc[j] = t + bopt[j];
  }
  __syncthreads();
  if (threadIdx.x==0){
    float logits[NCAT];
    #pragma unroll
    for (int j=0;j<NCAT;++j) logits[j]=sc[j];
    unsigned f0,f1;
    tf_block(nk[key_ofs], nk[key_ofs+1], 0u, (unsigned)(2+isub), f0, f1);
    int op = sample_and_stats(logits, f0, f1, scal);
    *outslot = (float)op;
    xctl_w[0] = 0; xctl_w[1] = op + 1;
  }
}

// ---------------- t2 = w2@h matvec with fused attention sample in last block ----------------
__global__ __launch_bounds__(256) void k_w2attn(
    const float* __restrict__ w2, const float* __restrict__ h,
    float* __restrict__ t2, const float* __restrict__ aw1,
    const float* __restrict__ vatt, const float* __restrict__ anch,
    float* __restrict__ x, float* __restrict__ scal,
    const unsigned* __restrict__ nk, int key_ofs, int isub, int svis,
    int* __restrict__ ctr, int* __restrict__ xctl_w, float* __restrict__ outslot)
{
  int wv = threadIdx.x>>6, ln = threadIdx.x&63;
  int r = blockIdx.x*4 + wv;                 // 512 blocks -> 2048 rows
  const float4* m4 = (const float4*)(w2 + (size_t)r*HDIM);
  const float4* h4 = (const float4*)h;
  float s = 0.f;
  #pragma unroll
  for (int it=0; it<8; ++it){
    float4 a = m4[ln+it*64]; float4 b = h4[ln+it*64];
    s += a.x*b.x + a.y*b.y + a.z*b.z + a.w*b.w;
  }
  #pragma unroll
  for (int m=32; m; m>>=1) s += __shfl_xor(s, m, 64);
  if (ln==0) t2[r] = s;

  __shared__ int slast;
  __shared__ float sc[NCAT];
  __shared__ int sidx;
  __syncthreads();
  if (threadIdx.x==0){
    __threadfence();
    int old = atomicAdd(ctr, 1);
    slast = (old == (int)gridDim.x - 1);
  }
  __syncthreads();
  if (!slast) return;
  __threadfence();
  const float4* t24 = (const float4*)t2;
  const float4* v4  = (const float4*)vatt;
  for (int j=wv; j<NCAT; j+=4){
    const float4* aj = (const float4*)(aw1 + (size_t)j*HDIM);
    float t = 0.f;
    for (int it=0; it<8; ++it){
      float4 tt = t24[ln+it*64], aa = aj[ln+it*64], vv = v4[ln+it*64];
      t += tanhf(tt.x+aa.x)*vv.x + tanhf(tt.y+aa.y)*vv.y
         + tanhf(tt.z+aa.z)*vv.z + tanhf(tt.w+aa.w)*vv.w;
    }
    #pragma unroll
    for (int m=32; m; m>>=1) t += __shfl_xor(t, m, 64);
    if (ln==0) sc[j] = t;
  }
  __syncthreads();
  if (threadIdx.x==0){
    float logits[NCAT];
    #pragma unroll
    for (int j=0;j<NCAT;++j) logits[j] = (j<svis)? sc[j] : -1e9f;
    unsigned f0,f1;
    tf_block(nk[key_ofs], nk[key_ofs+1], 0u, (unsigned)isub, f0, f1);
    int idx = sample_and_stats(logits, f0, f1, scal);
    *outslot = (float)idx;
    sidx = idx;
    xctl_w[0] = (idx < 2) ? 2 : 1;   // anchors 0,1 are all-zero -> skip w_ih entirely
    xctl_w[1] = 0;
  }
  __syncthreads();
  int si = sidx;
  if (si >= 2){
    const float4* src = (const float4*)(anch + (size_t)si*HDIM);
    float4* dst = (float4*)x;
    for (int i=threadIdx.x; i<512; i+=256) dst[i] = src[i];
  }
}

// ---------------- aw1[s] = w1@h (+ anchors[s]=h copy, + reset x to emb[0]) ----------------
__global__ __launch_bounds__(256) void k_w1post(const float* __restrict__ w1,
    const float* __restrict__ h, float* __restrict__ aw1s,
    float* __restrict__ anchs, int* __restrict__ xctl_w)
{
  int wv = threadIdx.x>>6, ln = threadIdx.x&63;
  int r = blockIdx.x*4 + wv;
  const float4* m4 = (const float4*)(w1 + (size_t)r*HDIM);
  const float4* h4 = (const float4*)h;
  float s = 0.f;
  #pragma unroll
  for (int it=0; it<8; ++it){
    float4 a = m4[ln+it*64]; float4 b = h4[ln+it*64];
    s += a.x*b.x + a.y*b.y + a.z*b.z + a.w*b.w;
  }
  #pragma unroll
  for (int m=32; m; m>>=1) s += __shfl_xor(s, m, 64);
  if (ln==0) aw1s[r] = s;
  if (anchs && threadIdx.x<4){
    int i = blockIdx.x*4 + threadIdx.x;
    anchs[i] = h[i];
  }
  if (blockIdx.x==0 && threadIdx.x==0){ xctl_w[0]=0; xctl_w[1]=0; }  // x = emb[0]
}

__global__ void k_fin(const float* __restrict__ scal, float* __restrict__ out){
  out[48] = scal[0];
  out[49] = scal[1];
}

extern "C" void kernel_launch(void* const* d_in, const int* in_sizes, int n_in,
                              void* d_out, int out_size, void* d_ws, size_t ws_size,
                              hipStream_t stream)
{
  (void)in_sizes; (void)n_in; (void)out_size; (void)ws_size;
  const float* emb   = (const float*)d_in[0];
  const float* w_ih  = (const float*)d_in[1];
  const float* w_hh  = (const float*)d_in[2];
  const float* b_ih  = (const float*)d_in[3];
  const float* b_hh  = (const float*)d_in[4];
  const float* w_opt = (const float*)d_in[5];
  const float* b_opt = (const float*)d_in[6];
  const float* w1    = (const float*)d_in[7];
  const float* w2    = (const float*)d_in[8];
  const float* vatt  = (const float*)d_in[9];
  const int*   seed  = (const int*)d_in[10];

  float* ws  = (float*)d_ws;
  float* out = (float*)d_out;

  float* h[2]  = { ws+WS_H0, ws+WS_H1 };
  float* c     = ws+WS_C;
  float* x     = ws+WS_X;
  float* t2    = ws+WS_T2;
  float* anch  = ws+WS_ANCH;
  float* aw1   = ws+WS_AW1;
  float* scal  = ws+WS_SCAL;
  int*   xctl  = (int*)(ws+WS_XCTL);
  const unsigned* nk = (const unsigned*)(ws+WS_NK);
  int*   ctr   = (int*)(ws+WS_CTR);
  float* bias  = ws+WS_BIAS;
  float* gie   = ws+WS_GIE;

  k_pre<<<2048,256,0,stream>>>(w_ih, b_ih, b_hh, emb, gie, bias);

  int cur = 0, ctr_id = 0;
  for (int cell=0; cell<2; ++cell){
    k_init<<<1,256,0,stream>>>(ws, seed, cell);
    // warmup: 2 LSTM steps (x=emb[0] via gie), aw1[s] = w1@h
    for (int s=0; s<2; ++s){
      k_lstm<<<2048,256,0,stream>>>(w_ih,w_hh,bias,gie,xctl,x,h[cur],h[cur^1],c,
                                    0,nullptr,nullptr,nullptr,nullptr,nullptr,0,0,nullptr,nullptr);
      cur^=1;
      k_w1post<<<512,256,0,stream>>>(w1, h[cur], aw1 + s*HDIM, nullptr, xctl);
    }
    for (int node=0; node<6; ++node){
      int key_ofs = (cell*6+node)*2;
      for (int i=0;i<2;++i){
        k_lstm<<<2048,256,0,stream>>>(w_ih,w_hh,bias,gie,xctl,x,h[cur],h[cur^1],c,
                                      0,nullptr,nullptr,nullptr,nullptr,nullptr,0,0,nullptr,nullptr);
        cur^=1;
        k_w2attn<<<512,256,0,stream>>>(w2, h[cur], t2, aw1, vatt, anch, x, scal,
                                       nk, key_ofs, i, node+2,
                                       ctr + ctr_id, xctl, out + cell*24 + node*2 + i);
        ctr_id++;
      }
      for (int i=0;i<2;++i){
        k_lstm<<<2048,256,0,stream>>>(w_ih,w_hh,bias,gie,xctl,x,h[cur],h[cur^1],c,
                                      1, ctr + ctr_id, w_opt, b_opt, scal, nk,
                                      key_ofs, i, out + cell*24 + 12 + node*2 + i, xctl);
        ctr_id++;
        cur^=1;
      }
      // trailing LSTM; anchors[s]=h, aw1[s]=w1@h, x=emb[0]
      k_lstm<<<2048,256,0,stream>>>(w_ih,w_hh,bias,gie,xctl,x,h[cur],h[cur^1],c,
                                    0,nullptr,nullptr,nullptr,nullptr,nullptr,0,0,nullptr,nullptr);
      cur^=1;
      k_w1post<<<512,256,0,stream>>>(w1, h[cur], aw1 + (node+2)*HDIM,
                                     anch + (node+2)*HDIM, xctl);
    }
  }
  k_fin<<<1,1,0,stream>>>(scal, out);
}

// Round 5
// 2414.822 us; speedup vs baseline: 1.3643x; 1.3643x over previous
//
#include <hip/hip_runtime.h>
#include <stdint.h>

// NAS LSTM controller on MI355X. Round 5 (= round 4 resubmit; broker timeouts):
// fp8-e4m3 weight compression (4x byte cut), XCD-sliced row ownership for
// cross-launch L2 residency, gie precompute for embedding-x steps, fused samplers.

#define HDIM 2048
#define NCAT 8
#define NROWS 8192
#define PARTITIONABLE 1   // modern JAX (>=0.4.30) default threefry mode

typedef float f32x2 __attribute__((ext_vector_type(2)));

// ---------------- workspace float offsets ----------------
#define WS_H0    0
#define WS_H1    2048
#define WS_C     4096
#define WS_X     6144
#define WS_T2    8192
#define WS_ANCH  10240     // 8 x 2048
#define WS_AW1   26624     // 8 x 2048
#define WS_SCAL  43008     // [ent, lp]
#define WS_XCTL  43010     // int xmode, int xidx
#define WS_NK    43012     // 24 u32 node keys
#define WS_CTR   43072     // 64 int counters
#define WS_BIAS  43264     // 8192 (b_ih + b_hh)
#define WS_GIE   51456     // 9 x 8192 f32 (w_ih@emb[j] + bias), exact
// byte offsets (from ws base) for fp8 weight copies
#define QB_IH    (512*1024)
#define QB_HH    (QB_IH + 16*1024*1024)
#define QB_W1    (QB_HH + 16*1024*1024)
#define QB_W2    (QB_W1 + 4*1024*1024)
// total ws need: ~40.5 MB

// ---------------- fp8 pack/unpack ----------------
__device__ __forceinline__ unsigned pack4_fp8(float4 a){
  int v = 0;
  v = __builtin_amdgcn_cvt_pk_fp8_f32(a.x, a.y, v, false);
  v = __builtin_amdgcn_cvt_pk_fp8_f32(a.z, a.w, v, true);
  return (unsigned)v;
}

// ---------------- threefry2x32 (20 rounds) ----------------
__device__ __forceinline__ unsigned rotl32(unsigned v, int r){ return (v<<r)|(v>>(32-r)); }

__device__ inline void tf_block(unsigned k0, unsigned k1, unsigned x0, unsigned x1,
                                unsigned& o0, unsigned& o1){
  unsigned ks0=k0, ks1=k1, ks2=0x1BD11BDAu ^ k0 ^ k1;
  const int ra[4]={13,15,26,6};
  const int rb[4]={17,29,16,24};
  x0 += ks0; x1 += ks1;
  #pragma unroll
  for (int i=0;i<4;++i){ x0+=x1; x1=rotl32(x1,ra[i]); x1^=x0; }
  x0+=ks1; x1+=ks2+1u;
  #pragma unroll
  for (int i=0;i<4;++i){ x0+=x1; x1=rotl32(x1,rb[i]); x1^=x0; }
  x0+=ks2; x1+=ks0+2u;
  #pragma unroll
  for (int i=0;i<4;++i){ x0+=x1; x1=rotl32(x1,ra[i]); x1^=x0; }
  x0+=ks0; x1+=ks1+3u;
  #pragma unroll
  for (int i=0;i<4;++i){ x0+=x1; x1=rotl32(x1,rb[i]); x1^=x0; }
  x0+=ks1; x1+=ks2+4u;
  #pragma unroll
  for (int i=0;i<4;++i){ x0+=x1; x1=rotl32(x1,ra[i]); x1^=x0; }
  x0+=ks2; x1+=ks0+5u;
  o0=x0; o1=x1;
}

__device__ __forceinline__ float sigm(float z){ return 1.0f/(1.0f+expf(-z)); }

__device__ inline int sample_and_stats(const float* logits, unsigned k0, unsigned k1,
                                       float* scal /* [ent, lp] */){
  unsigned bits[NCAT];
#if PARTITIONABLE
  #pragma unroll
  for (int i=0;i<NCAT;++i){ unsigned a,b; tf_block(k0,k1,0u,(unsigned)i,a,b); bits[i]=a^b; }
#else
  #pragma unroll
  for (int i=0;i<4;++i){ unsigned a,b; tf_block(k0,k1,(unsigned)i,(unsigned)(i+4),a,b); bits[i]=a; bits[i+4]=b; }
#endif
  const float tiny = 1.1754943508222875e-38f;
  int best=0; float bv=-3.4e38f;
  #pragma unroll
  for (int j=0;j<NCAT;++j){
    float f = __uint_as_float((bits[j]>>9)|0x3f800000u) - 1.0f;
    float u = fmaxf(tiny, f*(1.0f-tiny)+tiny);
    float g = -logf(-logf(u));
    float vv = g + logits[j];
    if (vv > bv){ bv=vv; best=j; }     // first-max wins, like jnp.argmax
  }
  float m=-3.4e38f;
  #pragma unroll
  for (int j=0;j<NCAT;++j) m = fmaxf(m, logits[j]);
  float se=0.f;
  #pragma unroll
  for (int j=0;j<NCAT;++j) se += expf(logits[j]-m);
  float lse = logf(se);
  scal[1] += (m + lse - logits[best]);            // lp += -logp[idx]
  float ent = 0.f;
  #pragma unroll
  for (int j=0;j<NCAT;++j){
    float lpj = logits[j]-m-lse;
    float p = expf(lpj);
    if (p > 0.f) ent -= p*lpj;                    // where(p>0, p*logp, 0)
  }
  scal[0] += ent;
  return best;
}

// ---------------- precompute: quantize weights to fp8, gie (exact f32), bias ----------------
// grid: 1024 (w_ih+gie) + 1024 (w_hh) + 256 (w1) + 256 (w2) = 2560 blocks x 256
__global__ __launch_bounds__(256) void k_pre(
    const float* __restrict__ w_ih, const float* __restrict__ w_hh,
    const float* __restrict__ w1, const float* __restrict__ w2,
    const float* __restrict__ b_ih, const float* __restrict__ b_hh,
    const float* __restrict__ emb,
    unsigned char* __restrict__ q_ih, unsigned char* __restrict__ q_hh,
    unsigned char* __restrict__ q_w1, unsigned char* __restrict__ q_w2,
    float* __restrict__ gie, float* __restrict__ bias)
{
  int b = blockIdx.x, wv = threadIdx.x>>6, ln = threadIdx.x&63;
  if (b < 1024){
    int r0 = b*8 + wv*2;
    const float4* s0 = (const float4*)(w_ih + (size_t)r0*HDIM);
    const float4* s1 = (const float4*)(w_ih + (size_t)(r0+1)*HDIM);
    unsigned* d0 = (unsigned*)(q_ih + (size_t)r0*HDIM);
    unsigned* d1 = (unsigned*)(q_ih + (size_t)(r0+1)*HDIM);
    const float4* e4 = (const float4*)emb;
    float acc0[9], acc1[9];
    #pragma unroll
    for (int j=0;j<9;++j){ acc0[j]=0.f; acc1[j]=0.f; }
    for (int it=0; it<8; ++it){
      int idx = ln + it*64;
      float4 a0 = s0[idx], a1 = s1[idx];
      d0[idx] = pack4_fp8(a0); d1[idx] = pack4_fp8(a1);
      #pragma unroll
      for (int j=0;j<9;++j){
        float4 e = e4[j*512 + idx];
        acc0[j] += a0.x*e.x + a0.y*e.y + a0.z*e.z + a0.w*e.w;
        acc1[j] += a1.x*e.x + a1.y*e.y + a1.z*e.z + a1.w*e.w;
      }
    }
    #pragma unroll
    for (int j=0;j<9;++j){
      float u = acc0[j], v = acc1[j];
      #pragma unroll
      for (int m=32;m;m>>=1){ u += __shfl_xor(u,m,64); v += __shfl_xor(v,m,64); }
      acc0[j]=u; acc1[j]=v;
    }
    if (ln==0){
      float bb0 = b_ih[r0]+b_hh[r0], bb1 = b_ih[r0+1]+b_hh[r0+1];
      bias[r0]=bb0; bias[r0+1]=bb1;
      #pragma unroll
      for (int j=0;j<9;++j){
        gie[(size_t)j*NROWS+r0]   = acc0[j]+bb0;
        gie[(size_t)j*NROWS+r0+1] = acc1[j]+bb1;
      }
    }
  } else {
    const float* src; unsigned char* dst; int r0;
    if (b < 2048){ src=w_hh; dst=q_hh; r0=(b-1024)*8 + wv*2; }
    else if (b < 2304){ src=w1; dst=q_w1; r0=(b-2048)*8 + wv*2; }
    else { src=w2; dst=q_w2; r0=(b-2304)*8 + wv*2; }
    const float4* s0 = (const float4*)(src + (size_t)r0*HDIM);
    const float4* s1 = (const float4*)(src + (size_t)(r0+1)*HDIM);
    unsigned* d0 = (unsigned*)(dst + (size_t)r0*HDIM);
    unsigned* d1 = (unsigned*)(dst + (size_t)(r0+1)*HDIM);
    for (int it=0; it<8; ++it){
      int idx = ln + it*64;
      d0[idx] = pack4_fp8(s0[idx]);
      d1[idx] = pack4_fp8(s1[idx]);
    }
  }
}

// ---------------- per-cell init ----------------
__global__ __launch_bounds__(256) void k_init(float* ws, const int* __restrict__ seedp, int cell){
  int t = threadIdx.x;
  float* anch = ws + WS_ANCH;
  float* aw1  = ws + WS_AW1;
  for (int i=t;i<NCAT*HDIM;i+=256){ anch[i]=0.f; aw1[i]=0.f; }
  if (cell==0){
    for (int i=t;i<HDIM;i+=256){ ws[WS_H0+i]=0.f; ws[WS_C+i]=0.f; }
    for (int i=t;i<64;i+=256) ((int*)(ws+WS_CTR))[i]=0;
  }
  if (t<2) ((int*)(ws+WS_XCTL))[t] = 0;       // xmode=0, xidx=0 (x = emb[0])
  if (t==0 && cell==0){
    ws[WS_SCAL]=0.f; ws[WS_SCAL+1]=0.f;
    unsigned* nk = (unsigned*)(ws + WS_NK);
    unsigned seed = (unsigned)seedp[0];
    unsigned K0=0u, K1=seed;
    unsigned ck[2][2];
#if PARTITIONABLE
    tf_block(K0,K1,0u,0u,ck[0][0],ck[0][1]);   // k1
    tf_block(K0,K1,0u,1u,ck[1][0],ck[1][1]);   // k2
    for (int cc=0;cc<2;++cc)
      for (int i=0;i<6;++i)
        tf_block(ck[cc][0],ck[cc][1],0u,(unsigned)i, nk[(cc*6+i)*2], nk[(cc*6+i)*2+1]);
#else
    unsigned a0,a1,b0,b1;
    tf_block(K0,K1,0u,2u,a0,a1);
    tf_block(K0,K1,1u,3u,b0,b1);
    ck[0][0]=a0; ck[0][1]=b0; ck[1][0]=a1; ck[1][1]=b1;
    for (int cc=0;cc<2;++cc){
      unsigned y0[6], y1[6];
      for (int i=0;i<6;++i) tf_block(ck[cc][0],ck[cc][1],(unsigned)i,(unsigned)(i+6),y0[i],y1[i]);
      unsigned flat[12];
      for (int i=0;i<6;++i){ flat[i]=y0[i]; flat[6+i]=y1[i]; }
      for (int i=0;i<6;++i){ nk[(cc*6+i)*2]=flat[2*i]; nk[(cc*6+i)*2+1]=flat[2*i+1]; }
    }
#endif
  }
}

// ---------------- LSTM step (fp8 weights) ----------------
// 512 blocks x 256. Block owns 4 hidden units (XCD-swizzled slab); wave wv = gate wv,
// 4 rows/wave. xmode: 0 = x=emb[xidx] (gie, skip w_ih); 1 = x=anchor (fp8 w_ih dot);
// 2 = x=0 (skip w_ih). post=1: last block fuses op-logits + sample + x=emb[op+1].
__global__ __launch_bounds__(256) void k_lstm(
    const unsigned char* __restrict__ q_ih, const unsigned char* __restrict__ q_hh,
    const float* __restrict__ bias, const float* __restrict__ gie,
    const int* __restrict__ xctl, const float* __restrict__ x,
    const float* __restrict__ h_in, float* __restrict__ h_out, float* __restrict__ c,
    int post, int* __restrict__ ctr,
    const float* __restrict__ wopt, const float* __restrict__ bopt,
    float* __restrict__ scal, const unsigned* __restrict__ nk,
    int key_ofs, int isub, float* __restrict__ outslot, int* __restrict__ xctl_w)
{
  __shared__ float gl[4][4];
  __shared__ int slast;
  __shared__ float sc[NCAT];

  int b  = blockIdx.x;
  int u0 = ((((b&7)<<6) | (b>>3)) << 2);     // XCD x owns units [x*256,(x+1)*256)
  int wv = threadIdx.x >> 6;
  int ln = threadIdx.x & 63;
  int xmode = xctl[0], xidx = xctl[1];

  // h columns for this lane (reused by all 4 rows)
  float4 hr[8];
  const float4* h4 = (const float4*)h_in;
  #pragma unroll
  for (int k=0;k<8;++k) hr[k] = h4[8*ln + k];

  size_t rbase = (size_t)wv*HDIM + u0;
  uint4 wq[4][2];
  #pragma unroll
  for (int rr=0;rr<4;++rr){
    const uint4* p = (const uint4*)(q_hh + (rbase+rr)*HDIM + 32*ln);
    wq[rr][0]=p[0]; wq[rr][1]=p[1];
  }
  float s[4];
  #pragma unroll
  for (int rr=0;rr<4;++rr){
    unsigned wd[8] = {wq[rr][0].x,wq[rr][0].y,wq[rr][0].z,wq[rr][0].w,
                      wq[rr][1].x,wq[rr][1].y,wq[rr][1].z,wq[rr][1].w};
    float t = 0.f;
    #pragma unroll
    for (int w=0;w<8;++w){
      f32x2 lo = __builtin_amdgcn_cvt_pk_f32_fp8((int)wd[w], false);
      f32x2 hi = __builtin_amdgcn_cvt_pk_f32_fp8((int)wd[w], true);
      t += lo.x*hr[w].x + lo.y*hr[w].y + hi.x*hr[w].z + hi.y*hr[w].w;
    }
    s[rr] = t;
  }
  if (xmode==1){
    float4 xr[8];
    const float4* x4 = (const float4*)x;
    #pragma unroll
    for (int k=0;k<8;++k) xr[k] = x4[8*ln + k];
    uint4 iq[4][2];
    #pragma unroll
    for (int rr=0;rr<4;++rr){
      const uint4* p = (const uint4*)(q_ih + (rbase+rr)*HDIM + 32*ln);
      iq[rr][0]=p[0]; iq[rr][1]=p[1];
    }
    #pragma unroll
    for (int rr=0;rr<4;++rr){
      unsigned wd[8] = {iq[rr][0].x,iq[rr][0].y,iq[rr][0].z,iq[rr][0].w,
                        iq[rr][1].x,iq[rr][1].y,iq[rr][1].z,iq[rr][1].w};
      float t = s[rr];
      #pragma unroll
      for (int w=0;w<8;++w){
        f32x2 lo = __builtin_amdgcn_cvt_pk_f32_fp8((int)wd[w], false);
        f32x2 hi = __builtin_amdgcn_cvt_pk_f32_fp8((int)wd[w], true);
        t += lo.x*xr[w].x + lo.y*xr[w].y + hi.x*xr[w].z + hi.y*xr[w].w;
      }
      s[rr] = t;
    }
  }
  #pragma unroll
  for (int rr=0;rr<4;++rr){
    float t = s[rr];
    #pragma unroll
    for (int m=32;m;m>>=1) t += __shfl_xor(t,m,64);
    if (ln==0) gl[wv][rr] = t;
  }
  __syncthreads();
  if (threadIdx.x < 4){
    int t = threadIdx.x, kk = u0 + t;
    float a0,a1,a2,a3;
    if (xmode==0){
      const float* gc = gie + (size_t)xidx*NROWS;
      a0=gc[kk]; a1=gc[HDIM+kk]; a2=gc[2*HDIM+kk]; a3=gc[3*HDIM+kk];
    } else {
      a0=bias[kk]; a1=bias[HDIM+kk]; a2=bias[2*HDIM+kk]; a3=bias[3*HDIM+kk];
    }
    float gi=gl[0][t]+a0, gf=gl[1][t]+a1, gg=gl[2][t]+a2, go=gl[3][t]+a3;
    float cn = sigm(gf)*c[kk] + sigm(gi)*tanhf(gg);
    c[kk] = cn;
    h_out[kk] = sigm(go)*tanhf(cn);
    if (post) __threadfence();           // each WRITER releases its own h_out store
  }
  if (!post) return;
  __syncthreads();
  if (threadIdx.x==0){
    slast = (atomicAdd(ctr,1) == (int)gridDim.x - 1);
  }
  __syncthreads();
  if (!slast) return;
  __threadfence();                       // acquire other blocks' h_out
  const float4* ho4 = (const float4*)h_out;
  for (int j=wv; j<NCAT; j+=4){
    const float4* wo = (const float4*)(wopt + (size_t)j*HDIM);
    float t = 0.f;
    #pragma unroll
    for (int it=0; it<8; ++it){
      float4 a = wo[ln+it*64]; float4 hh = ho4[ln+it*64];
      t += a.x*hh.x + a.y*hh.y + a.z*hh.z + a.w*hh.w;
    }
    #pragma unroll
    for (int m=32;m;m>>=1) t += __shfl_xor(t,m,64);
    if (ln==0) sc[j] = t + bopt[j];
  }
  __syncthreads();
  if (threadIdx.x==0){
    float logits[NCAT];
    #pragma unroll
    for (int j=0;j<NCAT;++j) logits[j]=sc[j];
    unsigned f0,f1;
    tf_block(nk[key_ofs], nk[key_ofs+1], 0u, (unsigned)(2+isub), f0, f1);
    int op = sample_and_stats(logits, f0, f1, scal);
    *outslot = (float)op;
    xctl_w[0] = 0; xctl_w[1] = op + 1;   // x = emb[op+1] via gie
  }
}

// ---------------- t2 = w2@h (fp8) + fused attention sample in last block ----------------
__global__ __launch_bounds__(256) void k_w2attn(
    const unsigned char* __restrict__ q_w2, const float* __restrict__ h,
    float* __restrict__ t2, const float* __restrict__ aw1,
    const float* __restrict__ vatt, const float* __restrict__ anch,
    float* __restrict__ x, float* __restrict__ scal,
    const unsigned* __restrict__ nk, int key_ofs, int isub, int svis,
    int* __restrict__ ctr, int* __restrict__ xctl_w, float* __restrict__ outslot)
{
  __shared__ int slast;
  __shared__ float sc[NCAT];
  __shared__ int sidx;
  int b = blockIdx.x, wv = threadIdx.x>>6, ln = threadIdx.x&63;
  int r = ((((b&7)<<6) | (b>>3)) << 2) + wv;   // XCD slabs of 256 rows

  float4 hr[8];
  const float4* h4 = (const float4*)h;
  #pragma unroll
  for (int k=0;k<8;++k) hr[k] = h4[8*ln + k];
  const uint4* p = (const uint4*)(q_w2 + (size_t)r*HDIM + 32*ln);
  uint4 qa = p[0], qb = p[1];
  unsigned wd[8] = {qa.x,qa.y,qa.z,qa.w,qb.x,qb.y,qb.z,qb.w};
  float s = 0.f;
  #pragma unroll
  for (int w=0;w<8;++w){
    f32x2 lo = __builtin_amdgcn_cvt_pk_f32_fp8((int)wd[w], false);
    f32x2 hi = __builtin_amdgcn_cvt_pk_f32_fp8((int)wd[w], true);
    s += lo.x*hr[w].x + lo.y*hr[w].y + hi.x*hr[w].z + hi.y*hr[w].w;
  }
  #pragma unroll
  for (int m=32;m;m>>=1) s += __shfl_xor(s,m,64);
  if (ln==0){
    t2[r] = s;
    __threadfence();                 // writer releases its own t2 store
  }
  __syncthreads();
  if (threadIdx.x==0){
    slast = (atomicAdd(ctr,1) == (int)gridDim.x - 1);
  }
  __syncthreads();
  if (!slast) return;
  __threadfence();                   // acquire all blocks' t2
  const float4* t24 = (const float4*)t2;
  const float4* v4  = (const float4*)vatt;
  for (int j=wv; j<NCAT; j+=4){
    const float4* aj = (const float4*)(aw1 + (size_t)j*HDIM);
    float t = 0.f;
    for (int it=0; it<8; ++it){
      float4 tt = t24[ln+it*64], aa = aj[ln+it*64], vv = v4[ln+it*64];
      t += tanhf(tt.x+aa.x)*vv.x + tanhf(tt.y+aa.y)*vv.y
         + tanhf(tt.z+aa.z)*vv.z + tanhf(tt.w+aa.w)*vv.w;
    }
    #pragma unroll
    for (int m=32;m;m>>=1) t += __shfl_xor(t,m,64);
    if (ln==0) sc[j] = t;
  }
  __syncthreads();
  if (threadIdx.x==0){
    float logits[NCAT];
    #pragma unroll
    for (int j=0;j<NCAT;++j) logits[j] = (j<svis)? sc[j] : -1e9f;
    unsigned f0,f1;
    tf_block(nk[key_ofs], nk[key_ofs+1], 0u, (unsigned)isub, f0, f1);
    int idx = sample_and_stats(logits, f0, f1, scal);
    *outslot = (float)idx;
    sidx = idx;
    xctl_w[0] = (idx < 2) ? 2 : 1;   // anchors 0,1 are all-zero -> skip w_ih entirely
    xctl_w[1] = 0;
  }
  __syncthreads();
  int si = sidx;
  if (si >= 2){
    const float4* src = (const float4*)(anch + (size_t)si*HDIM);
    float4* dst = (float4*)x;
    for (int i=threadIdx.x; i<512; i+=256) dst[i] = src[i];
  }
}

// ---------------- aw1[s] = w1@h (fp8) + anchors[s]=h copy + x reset ----------------
__global__ __launch_bounds__(256) void k_w1post(const unsigned char* __restrict__ q_w1,
    const float* __restrict__ h, float* __restrict__ aw1s,
    float* __restrict__ anchs, int* __restrict__ xctl_w)
{
  int b = blockIdx.x, wv = threadIdx.x>>6, ln = threadIdx.x&63;
  int r = ((((b&7)<<6) | (b>>3)) << 2) + wv;

  float4 hr[8];
  const float4* h4 = (const float4*)h;
  #pragma unroll
  for (int k=0;k<8;++k) hr[k] = h4[8*ln + k];
  const uint4* p = (const uint4*)(q_w1 + (size_t)r*HDIM + 32*ln);
  uint4 qa = p[0], qb = p[1];
  unsigned wd[8] = {qa.x,qa.y,qa.z,qa.w,qb.x,qb.y,qb.z,qb.w};
  float s = 0.f;
  #pragma unroll
  for (int w=0;w<8;++w){
    f32x2 lo = __builtin_amdgcn_cvt_pk_f32_fp8((int)wd[w], false);
    f32x2 hi = __builtin_amdgcn_cvt_pk_f32_fp8((int)wd[w], true);
    s += lo.x*hr[w].x + lo.y*hr[w].y + hi.x*hr[w].z + hi.y*hr[w].w;
  }
  #pragma unroll
  for (int m=32;m;m>>=1) s += __shfl_xor(s,m,64);
  if (ln==0) aw1s[r] = s;
  if (anchs && threadIdx.x<4){
    int i = b*4 + threadIdx.x;
    anchs[i] = h[i];
  }
  if (b==0 && threadIdx.x==0){ xctl_w[0]=0; xctl_w[1]=0; }  // x = emb[0]
}

__global__ void k_fin(const float* __restrict__ scal, float* __restrict__ out){
  out[48] = scal[0];
  out[49] = scal[1];
}

extern "C" void kernel_launch(void* const* d_in, const int* in_sizes, int n_in,
                              void* d_out, int out_size, void* d_ws, size_t ws_size,
                              hipStream_t stream)
{
  (void)in_sizes; (void)n_in; (void)out_size; (void)ws_size;
  const float* emb   = (const float*)d_in[0];
  const float* w_ih  = (const float*)d_in[1];
  const float* w_hh  = (const float*)d_in[2];
  const float* b_ih  = (const float*)d_in[3];
  const float* b_hh  = (const float*)d_in[4];
  const float* w_opt = (const float*)d_in[5];
  const float* b_opt = (const float*)d_in[6];
  const float* w1    = (const float*)d_in[7];
  const float* w2    = (const float*)d_in[8];
  const float* vatt  = (const float*)d_in[9];
  const int*   seed  = (const int*)d_in[10];

  float* ws  = (float*)d_ws;
  float* out = (float*)d_out;
  unsigned char* wsb = (unsigned char*)d_ws;

  float* h[2]  = { ws+WS_H0, ws+WS_H1 };
  float* c     = ws+WS_C;
  float* x     = ws+WS_X;
  float* t2    = ws+WS_T2;
  float* anch  = ws+WS_ANCH;
  float* aw1   = ws+WS_AW1;
  float* scal  = ws+WS_SCAL;
  int*   xctl  = (int*)(ws+WS_XCTL);
  const unsigned* nk = (const unsigned*)(ws+WS_NK);
  int*   ctr   = (int*)(ws+WS_CTR);
  float* bias  = ws+WS_BIAS;
  float* gie   = ws+WS_GIE;
  unsigned char* q_ih = wsb + QB_IH;
  unsigned char* q_hh = wsb + QB_HH;
  unsigned char* q_w1 = wsb + QB_W1;
  unsigned char* q_w2 = wsb + QB_W2;

  k_pre<<<2560,256,0,stream>>>(w_ih, w_hh, w1, w2, b_ih, b_hh, emb,
                               q_ih, q_hh, q_w1, q_w2, gie, bias);

  int cur = 0, ctr_id = 0;
  for (int cell=0; cell<2; ++cell){
    k_init<<<1,256,0,stream>>>(ws, seed, cell);
    for (int s=0; s<2; ++s){
      k_lstm<<<512,256,0,stream>>>(q_ih,q_hh,bias,gie,xctl,x,h[cur],h[cur^1],c,
                                   0,nullptr,nullptr,nullptr,nullptr,nullptr,0,0,nullptr,nullptr);
      cur^=1;
      k_w1post<<<512,256,0,stream>>>(q_w1, h[cur], aw1 + s*HDIM, nullptr, xctl);
    }
    for (int node=0; node<6; ++node){
      int key_ofs = (cell*6+node)*2;
      for (int i=0;i<2;++i){
        k_lstm<<<512,256,0,stream>>>(q_ih,q_hh,bias,gie,xctl,x,h[cur],h[cur^1],c,
                                     0,nullptr,nullptr,nullptr,nullptr,nullptr,0,0,nullptr,nullptr);
        cur^=1;
        k_w2attn<<<512,256,0,stream>>>(q_w2, h[cur], t2, aw1, vatt, anch, x, scal,
                                       nk, key_ofs, i, node+2,
                                       ctr + ctr_id, xctl, out + cell*24 + node*2 + i);
        ctr_id++;
      }
      for (int i=0;i<2;++i){
        k_lstm<<<512,256,0,stream>>>(q_ih,q_hh,bias,gie,xctl,x,h[cur],h[cur^1],c,
                                     1, ctr + ctr_id, w_opt, b_opt, scal, nk,
                                     key_ofs, i, out + cell*24 + 12 + node*2 + i, xctl);
        ctr_id++;
        cur^=1;
      }
      k_lstm<<<512,256,0,stream>>>(q_ih,q_hh,bias,gie,xctl,x,h[cur],h[cur^1],c,
                                   0,nullptr,nullptr,nullptr,nullptr,nullptr,0,0,nullptr,nullptr);
      cur^=1;
      k_w1post<<<512,256,0,stream>>>(q_w1, h[cur], aw1 + (node+2)*HDIM,
                                     anch + (node+2)*HDIM, xctl);
    }
  }
  k_fin<<<1,1,0,stream>>>(scal, out);
}